// Round 1
// 1143.214 us; speedup vs baseline: 1.1297x; 1.1297x over previous
//
#include <hip/hip_runtime.h>

typedef __bf16 bf16_t;
typedef __bf16 bf16x8 __attribute__((ext_vector_type(8)));
typedef float f32x4 __attribute__((ext_vector_type(4)));

// ---------------------------------------------------------------------------
// GEMM: C[M][N] = A[M][K] @ Bt[N][K]^T + bias[N], optional relu,
// writes fp32 and/or bf16 outputs. 128x128 tile, BK=32, 4 waves, 4x4 MFMA
// 16x16x32 per wave. Bt is bf16 row-major, K contiguous.
//   AF32: A is read as fp32 and converted to bf16 in registers (A ptr = Af).
//   kChunk > 0: split-K; blockIdx.z = chunk; partial z written to
//               Cf + z*M*N; bias added only by chunk 0; Cbf must be null.
//   kChunk == 0 && zStride != 0: batched mode; A/Bt/Cf/Cbf offset z*zStride.
// ---------------------------------------------------------------------------
#define BM 128
#define BN 128
#define BK 32
#define LDK 40  // padded LDS row stride (elements); 80 B = multiple of 16 B

__device__ inline uint4 pack_bf16x8(float4 a, float4 b)
{
    union { bf16_t h[8]; uint4 u; } cv;
    cv.h[0] = (bf16_t)a.x; cv.h[1] = (bf16_t)a.y;
    cv.h[2] = (bf16_t)a.z; cv.h[3] = (bf16_t)a.w;
    cv.h[4] = (bf16_t)b.x; cv.h[5] = (bf16_t)b.y;
    cv.h[6] = (bf16_t)b.z; cv.h[7] = (bf16_t)b.w;
    return cv.u;
}

template<bool AF32>
__global__ __launch_bounds__(256, 2)
void gemm_bf16(const bf16_t* __restrict__ A, const float* __restrict__ Af,
               const bf16_t* __restrict__ Bt, const float* __restrict__ bias,
               float* __restrict__ Cf, bf16_t* __restrict__ Cbf,
               int M, int N, int K, int relu, int kChunk, long zStride)
{
    __shared__ bf16_t As[BM * LDK];
    __shared__ bf16_t Bs[BN * LDK];

    const int tid  = threadIdx.x;
    const int m0   = blockIdx.y * BM;
    const int n0   = blockIdx.x * BN;
    const int z    = blockIdx.z;
    const int wave = tid >> 6;
    const int lane = tid & 63;
    const int wm   = (wave & 1) * 64;   // wave row offset in block tile
    const int wn   = (wave >> 1) * 64;  // wave col offset
    const int lr   = lane & 15;         // A row / B col within 16-tile
    const int lq   = lane >> 4;         // quad 0..3 -> k-offset lq*8

    int kBeg = 0, kEnd = K;
    const float* biasP = bias;
    if (kChunk > 0) {
        kBeg = z * kChunk;
        kEnd = min(K, kBeg + kChunk);
        Cf  += (long)z * M * N;         // deterministic partial per chunk
        if (z != 0) biasP = nullptr;    // bias added exactly once (chunk 0)
    } else if (zStride != 0) {
        if constexpr (AF32) Af += (long)z * zStride;
        else                A  += (long)z * zStride;
        Bt += (long)z * zStride;
        if (Cf)  Cf  += (long)z * zStride;
        if (Cbf) Cbf += (long)z * zStride;
    }

    f32x4 acc[4][4];
#pragma unroll
    for (int i = 0; i < 4; i++)
#pragma unroll
        for (int j = 0; j < 4; j++) acc[i][j] = (f32x4){0.f, 0.f, 0.f, 0.f};

    // staging: 512 chunks of 8 bf16 per tile; 256 threads x 2 chunks
    const int c0 = tid, c1 = tid + 256;
    const int ar0 = c0 >> 2, ak0 = (c0 & 3) * 8;
    const int ar1 = c1 >> 2, ak1 = (c1 & 3) * 8;

    const bf16_t* Bptr = Bt + (long)n0 * K;

    for (int k0 = kBeg; k0 < kEnd; k0 += BK) {
        uint4 av0, av1;
        if constexpr (AF32) {
            const float* p0 = Af + (long)(m0 + ar0) * K + k0 + ak0;
            const float* p1 = Af + (long)(m0 + ar1) * K + k0 + ak1;
            float4 a00 = *(const float4*)p0, a01 = *(const float4*)(p0 + 4);
            float4 a10 = *(const float4*)p1, a11 = *(const float4*)(p1 + 4);
            av0 = pack_bf16x8(a00, a01);
            av1 = pack_bf16x8(a10, a11);
        } else {
            av0 = *(const uint4*)(A + (long)(m0 + ar0) * K + k0 + ak0);
            av1 = *(const uint4*)(A + (long)(m0 + ar1) * K + k0 + ak1);
        }
        uint4 bv0 = *(const uint4*)(Bptr + (long)ar0 * K + k0 + ak0);
        uint4 bv1 = *(const uint4*)(Bptr + (long)ar1 * K + k0 + ak1);
        __syncthreads();  // previous iteration's LDS reads complete
        *(uint4*)&As[ar0 * LDK + ak0] = av0;
        *(uint4*)&As[ar1 * LDK + ak1] = av1;
        *(uint4*)&Bs[ar0 * LDK + ak0] = bv0;
        *(uint4*)&Bs[ar1 * LDK + ak1] = bv1;
        __syncthreads();

        bf16x8 af[4], bfr[4];
#pragma unroll
        for (int i = 0; i < 4; i++) {
            af[i]  = *(bf16x8*)&As[(wm + i * 16 + lr) * LDK + lq * 8];
            bfr[i] = *(bf16x8*)&Bs[(wn + i * 16 + lr) * LDK + lq * 8];
        }
#pragma unroll
        for (int i = 0; i < 4; i++)
#pragma unroll
            for (int j = 0; j < 4; j++)
                acc[i][j] = __builtin_amdgcn_mfma_f32_16x16x32_bf16(
                    af[i], bfr[j], acc[i][j], 0, 0, 0);
    }

    // epilogue: D row = m0+wm+i*16+lq*4+r, col = n0+wn+j*16+lr
#pragma unroll
    for (int i = 0; i < 4; i++) {
#pragma unroll
        for (int j = 0; j < 4; j++) {
            const int col = n0 + wn + j * 16 + lr;
            const float bval = biasP ? biasP[col] : 0.f;
#pragma unroll
            for (int r = 0; r < 4; r++) {
                const int row = m0 + wm + i * 16 + lq * 4 + r;
                float v = acc[i][j][r] + bval;
                if (relu) v = fmaxf(v, 0.f);
                const long idx = (long)row * N + col;
                if (Cf)  Cf[idx] = v;
                if (Cbf) Cbf[idx] = (bf16_t)v;
            }
        }
    }
}

// ---------------------------------------------------------------------------
// transpose + cast: in fp32 [R][C] row-major  ->  out bf16 [C][R] row-major
// R, C multiples of 32. block (32,8), 32x32 tiles, z = batch.
// ---------------------------------------------------------------------------
__global__ void transpose_cast(const float* __restrict__ in, bf16_t* __restrict__ out,
                               int R, int C, long inStrideZ, long outStrideZ)
{
    __shared__ float t[32][33];
    const float* inz = in + inStrideZ * blockIdx.z;
    bf16_t* outz = out + outStrideZ * blockIdx.z;
    const int c0 = blockIdx.x * 32;
    const int r0 = blockIdx.y * 32;
    const int tx = threadIdx.x, ty = threadIdx.y;
#pragma unroll
    for (int dy = 0; dy < 32; dy += 8)
        t[ty + dy][tx] = inz[(long)(r0 + ty + dy) * C + c0 + tx];
    __syncthreads();
#pragma unroll
    for (int dy = 0; dy < 32; dy += 8)
        outz[(long)(c0 + ty + dy) * R + r0 + tx] = (bf16_t)t[tx][ty + dy];
}

// ---------------------------------------------------------------------------
// WvN[i][d][h*64+e] = Wv[i][h][d][e]  (fp32 -> bf16), i.e. Wv_flat per layer
// ---------------------------------------------------------------------------
__global__ void build_wvn(const float* __restrict__ Wv, bf16_t* __restrict__ WvN)
{
    const long o = (long)blockIdx.x * 256 + threadIdx.x;  // 4*768*768 total
    const int e = (int)(o & 63);
    const int h = (int)((o >> 6) % 12);
    const long t = o / 768;
    const int d = (int)(t % 768);
    const int i = (int)(t / 768);
    WvN[o] = (bf16_t)Wv[(((long)(i * 12 + h) * 768 + d) << 6) + e];
}

// ---------------------------------------------------------------------------
// bvo[i][j] = bo[i][j] + sum_n bv[i][n] * Wo[i][n][j]   (all fp32, exact)
// ---------------------------------------------------------------------------
__global__ __launch_bounds__(256)
void build_bvo(const float* __restrict__ Wo, const float* __restrict__ bv,
               const float* __restrict__ bo, float* __restrict__ bvo)
{
    const int i = blockIdx.y;
    const int j = blockIdx.x * 256 + threadIdx.x;
    const float* w = Wo + (long)i * 589824 + j;
    const float* b = bv + i * 768;
    float s = bo[i * 768 + j];
    for (int n = 0; n < 768; n++) s += b[n] * w[(long)n * 768];
    bvo[i * 768 + j] = s;
}

// ---------------------------------------------------------------------------
// out = sum of nP partials (fp32), plus bf16 copy. 4 elems/thread.
// ---------------------------------------------------------------------------
__global__ __launch_bounds__(256)
void reduce_cast(const float* __restrict__ P, long pStride, int nP,
                 float* __restrict__ outF, bf16_t* __restrict__ outBf, long n)
{
    const long i = ((long)blockIdx.x * 256 + threadIdx.x) * 4;
    if (i >= n) return;
    float4 s = *(const float4*)(P + i);
    for (int p = 1; p < nP; p++) {
        float4 t = *(const float4*)(P + (long)p * pStride + i);
        s.x += t.x; s.y += t.y; s.z += t.z; s.w += t.w;
    }
    *(float4*)(outF + i) = s;
    union { bf16_t h[4]; uint2 u; } cv;
    cv.h[0] = (bf16_t)s.x; cv.h[1] = (bf16_t)s.y;
    cv.h[2] = (bf16_t)s.z; cv.h[3] = (bf16_t)s.w;
    *(uint2*)(outBf + i) = cv.u;
}

// ---------------------------------------------------------------------------
// X = LayerNorm(X + sum of nP partials)  (population var, no eps, no affine),
// writes fp32 + bf16. one block per row, D = 768, 256 threads x 3 elems
// ---------------------------------------------------------------------------
__global__ __launch_bounds__(256)
void ln_residual(float* __restrict__ X, const float* __restrict__ P,
                 long pStride, int nP, bf16_t* __restrict__ Xbf)
{
    __shared__ float red[8];
    const long base = (long)blockIdx.x * 768;
    const int tid = threadIdx.x;
    float s[3];
#pragma unroll
    for (int j = 0; j < 3; j++) {
        const int idx = tid + j * 256;
        float v = X[base + idx];
        for (int p = 0; p < nP; p++) v += P[(long)p * pStride + base + idx];
        s[j] = v;
    }
    float sum = s[0] + s[1] + s[2];
    for (int o = 32; o > 0; o >>= 1) sum += __shfl_down(sum, o, 64);
    if ((tid & 63) == 0) red[tid >> 6] = sum;
    __syncthreads();
    const float mu = (red[0] + red[1] + red[2] + red[3]) * (1.0f / 768.0f);
    float d0 = s[0] - mu, d1 = s[1] - mu, d2 = s[2] - mu;
    float sq = d0 * d0 + d1 * d1 + d2 * d2;
    for (int o = 32; o > 0; o >>= 1) sq += __shfl_down(sq, o, 64);
    if ((tid & 63) == 0) red[4 + (tid >> 6)] = sq;
    __syncthreads();
    const float var = (red[4] + red[5] + red[6] + red[7]) * (1.0f / 768.0f);
    const float rstd = 1.0f / sqrtf(var);
#pragma unroll
    for (int j = 0; j < 3; j++) {
        const int idx = tid + j * 256;
        const float v = (s[j] - mu) * rstd;
        X[base + idx] = v;
        Xbf[base + idx] = (bf16_t)v;
    }
}

// ---------------------------------------------------------------------------
// in-place row softmax over 8192 cols; one block per row, 32 elems/thread
// ---------------------------------------------------------------------------
__global__ __launch_bounds__(256)
void softmax_inplace(float* __restrict__ P)
{
    __shared__ float red[8];
    const long base = (long)blockIdx.x * 8192;
    const int tid = threadIdx.x;
    float v[32];
    float mx = -1e30f;
#pragma unroll
    for (int j = 0; j < 32; j++) {
        v[j] = P[base + tid + j * 256];
        mx = fmaxf(mx, v[j]);
    }
    for (int o = 32; o > 0; o >>= 1) mx = fmaxf(mx, __shfl_down(mx, o, 64));
    if ((tid & 63) == 0) red[tid >> 6] = mx;
    __syncthreads();
    mx = fmaxf(fmaxf(red[0], red[1]), fmaxf(red[2], red[3]));
    float sum = 0.f;
#pragma unroll
    for (int j = 0; j < 32; j++) {
        v[j] = __expf(v[j] - mx);
        sum += v[j];
    }
    for (int o = 32; o > 0; o >>= 1) sum += __shfl_down(sum, o, 64);
    if ((tid & 63) == 0) red[4 + (tid >> 6)] = sum;
    __syncthreads();
    const float inv = 1.0f / (red[4] + red[5] + red[6] + red[7]);
#pragma unroll
    for (int j = 0; j < 32; j++) P[base + tid + j * 256] = v[j] * inv;
}

// ---------------------------------------------------------------------------
extern "C" void kernel_launch(void* const* d_in, const int* in_sizes, int n_in,
                              void* d_out, int out_size, void* d_ws, size_t ws_size,
                              hipStream_t stream)
{
    (void)in_sizes; (void)n_in; (void)out_size; (void)ws_size;
    const float* X0   = (const float*)d_in[0];
    const float* embw = (const float*)d_in[1];
    const float* embb = (const float*)d_in[2];
    // d_in[3..6] = Wq,bq,Wk,bk : unused (softmax rows sum to 1 => head_out == V)
    const float* Wv   = (const float*)d_in[7];
    const float* bv   = (const float*)d_in[8];
    const float* Wo   = (const float*)d_in[9];
    const float* bo   = (const float*)d_in[10];
    const float* W1   = (const float*)d_in[11];
    const float* b1   = (const float*)d_in[12];
    const float* W2   = (const float*)d_in[13];
    const float* b2   = (const float*)d_in[14];
    const float* Wout = (const float*)d_in[15];
    const float* bout = (const float*)d_in[16];
    float* out = (float*)d_out;

    // workspace layout (~142.5 MB). The 50.3 MB P region is time-shared:
    //   phase 0 (weight prep): WvN (4.72 MB) + WoT (4.72 MB) transients
    //   phase 1..layers:       split-K partials P[0..3], each [4096][768] f32
    //   phase 2 (output):      WoutT bf16 [8192][768]
    char* base = (char*)d_ws;
    float*  P     = (float*)base;                       // 50,331,648 B
    bf16_t* WvN   = (bf16_t*)base;                      // transient alias
    bf16_t* WoT   = (bf16_t*)(base + 4718592);          // transient alias
    bf16_t* WoutT = (bf16_t*)base;                      // final-phase alias
    bf16_t* Hid   = (bf16_t*)(base + 50331648);         // 25,165,824 B
    bf16_t* embT  = (bf16_t*)(base + 75497472);         // 12,582,912 B
    bf16_t* WvoT  = (bf16_t*)(base + 88080384);         //  4,718,592 B
    float*  bvo   = (float*)(base + 92798976);          //     12,288 B
    bf16_t* W1T   = (bf16_t*)(base + 92811264);         // 18,874,368 B
    bf16_t* W2T   = (bf16_t*)(base + 111685632);        // 18,874,368 B
    float*  Xf    = (float*)(base + 130560000);         // 12,582,912 B
    bf16_t* Xbf   = (bf16_t*)(base + 143142912);        //  6,291,456 B

    const dim3 tb(32, 8);
    const long MN = 3145728;  // 4096*768, partial stride

    // ---- phase 0: weight prep ------------------------------------------
    transpose_cast<<<dim3(24, 256, 1), tb, 0, stream>>>(embw, embT, 8192, 768, 0, 0);
    transpose_cast<<<dim3(24, 24, 4), tb, 0, stream>>>(Wo, WoT, 768, 768, 589824, 589824);
    build_wvn<<<9216, 256, 0, stream>>>(Wv, WvN);
    build_bvo<<<dim3(3, 4), 256, 0, stream>>>(Wo, bv, bo, bvo);
    // WvoT[i][j][d] = sum_n Wo[i][n][j] * Wv_flat[i][d][n]  (batched, bf16 out)
    gemm_bf16<false><<<dim3(6, 6, 4), 256, 0, stream>>>(
        WoT, nullptr, WvN, nullptr, nullptr, WvoT, 768, 768, 768, 0, 0, 589824L);
    transpose_cast<<<dim3(96, 24, 4), tb, 0, stream>>>(W1, W1T, 768, 3072, 2359296, 2359296);
    transpose_cast<<<dim3(24, 96, 4), tb, 0, stream>>>(W2, W2T, 3072, 768, 2359296, 2359296);

    // ---- phase 1: embedding, split-K=4, fp32 A read directly -----------
    gemm_bf16<true><<<dim3(6, 32, 4), 256, 0, stream>>>(
        nullptr, X0, embT, embb, P, nullptr, 4096, 768, 8192, 0, 2048, 0);
    reduce_cast<<<3072, 256, 0, stream>>>(P, MN, 4, Xf, Xbf, MN);

    // ---- layers ---------------------------------------------------------
    for (int i = 0; i < 4; i++) {
        // O = X @ Wvo + bvo   (V and O GEMMs fused), split-K=2
        gemm_bf16<false><<<dim3(6, 32, 2), 256, 0, stream>>>(
            Xbf, nullptr, WvoT + (size_t)i * 589824, bvo + i * 768, P, nullptr,
            4096, 768, 768, 0, 384, 0);
        ln_residual<<<4096, 256, 0, stream>>>(Xf, P, MN, 2, Xbf);
        // Hid = relu(X @ W1 + b1)  (grid 768, no split needed)
        gemm_bf16<false><<<dim3(24, 32), 256, 0, stream>>>(
            Xbf, nullptr, W1T + (size_t)i * 2359296, b1 + i * 3072, nullptr, Hid,
            4096, 3072, 768, 1, 0, 0);
        // F = Hid @ W2 + b2, split-K=4
        gemm_bf16<false><<<dim3(6, 32, 4), 256, 0, stream>>>(
            Hid, nullptr, W2T + (size_t)i * 2359296, b2 + i * 768, P, nullptr,
            4096, 768, 3072, 0, 768, 0);
        ln_residual<<<4096, 256, 0, stream>>>(Xf, P, MN, 4, Xbf);
    }

    // ---- phase 2: output head ------------------------------------------
    transpose_cast<<<dim3(256, 24, 1), tb, 0, stream>>>(Wout, WoutT, 768, 8192, 0, 0);
    gemm_bf16<false><<<dim3(64, 32), 256, 0, stream>>>(
        Xbf, nullptr, WoutT, bout, out, nullptr, 4096, 8192, 768, 0, 0, 0);
    softmax_inplace<<<4096, 256, 0, stream>>>(out);
}

// Round 2
// 1086.769 us; speedup vs baseline: 1.1884x; 1.0519x over previous
//
#include <hip/hip_runtime.h>

typedef __bf16 bf16_t;
typedef __bf16 bf16x4 __attribute__((ext_vector_type(4)));
typedef __bf16 bf16x8 __attribute__((ext_vector_type(8)));
typedef float f32x4 __attribute__((ext_vector_type(4)));

// ---------------------------------------------------------------------------
// GEMM: C[M][N] = A[M][K] @ Bt[N][K]^T + bias[N], optional relu,
// writes fp32 and/or bf16 outputs. 128x128 tile, BK=32, 4 waves, 4x4 MFMA
// 16x16x32 per wave. Bt is bf16 row-major, K contiguous.
//   AF32: A is read as fp32 and converted to bf16 in registers (A ptr = Af).
//   kChunk > 0: split-K; z = chunk; partial z written to (Cbf?Cbf:Cf)+z*M*N;
//               bias added only by chunk 0.
//   kChunk == 0 && zStride != 0: batched mode; A/Bt/Cf/Cbf offset z*zStride.
// All launches must satisfy (gridDim.y*gridDim.z) % 8 == 0 OR gridDim.y*
// gridDim.z small-multiple cases listed below (all current launches comply).
// ---------------------------------------------------------------------------
#define BM 128
#define BN 128
#define BK 32
#define LDK 40  // padded LDS row stride (elements); 80 B = multiple of 16 B

__device__ inline uint4 pack_bf16x8(float4 a, float4 b)
{
    union { bf16_t h[8]; uint4 u; } cv;
    cv.h[0] = (bf16_t)a.x; cv.h[1] = (bf16_t)a.y;
    cv.h[2] = (bf16_t)a.z; cv.h[3] = (bf16_t)a.w;
    cv.h[4] = (bf16_t)b.x; cv.h[5] = (bf16_t)b.y;
    cv.h[6] = (bf16_t)b.z; cv.h[7] = (bf16_t)b.w;
    return cv.u;
}

template<bool AF32>
__global__ __launch_bounds__(256, 2)
void gemm_bf16(const bf16_t* __restrict__ A, const float* __restrict__ Af,
               const bf16_t* __restrict__ Bt, const float* __restrict__ bias,
               float* __restrict__ Cf, bf16_t* __restrict__ Cbf,
               int M, int N, int K, int relu, int kChunk, long zStride)
{
    __shared__ bf16_t As[BM * LDK];
    __shared__ bf16_t Bs[BN * LDK];

    // Bijective XCD swizzle (m204-style): co-locate blocks sharing the same
    // A row-panel (same y,z; different x) on one XCD for L2 A-reuse.
    // Requires (gridDim.y * gridDim.z) % 8 == 0 for bijectivity.
    const int gx = gridDim.x, gy = gridDim.y;
    const long L = blockIdx.x + (long)gx * (blockIdx.y + (long)gy * blockIdx.z);
    const int  r = (int)(L & 7);
    const long t = L >> 3;
    const int  bx = (int)(t % gx);
    const long g  = r + 8 * (t / gx);
    const int  by = (int)(g % gy);
    const int  bz = (int)(g / gy);

    const int tid  = threadIdx.x;
    const int m0   = by * BM;
    const int n0   = bx * BN;
    const int z    = bz;
    const int wave = tid >> 6;
    const int lane = tid & 63;
    const int wm   = (wave & 1) * 64;   // wave row offset in block tile
    const int wn   = (wave >> 1) * 64;  // wave col offset
    const int lr   = lane & 15;         // A row / B col within 16-tile
    const int lq   = lane >> 4;         // quad 0..3 -> k-offset lq*8

    int kBeg = 0, kEnd = K;
    const float* biasP = bias;
    if (kChunk > 0) {
        kBeg = z * kChunk;
        kEnd = min(K, kBeg + kChunk);
        if (Cbf) Cbf += (long)z * M * N;   // deterministic bf16 partial
        else     Cf  += (long)z * M * N;
        if (z != 0) biasP = nullptr;       // bias added exactly once (chunk 0)
    } else if (zStride != 0) {
        if constexpr (AF32) Af += (long)z * zStride;
        else                A  += (long)z * zStride;
        Bt += (long)z * zStride;
        if (Cf)  Cf  += (long)z * zStride;
        if (Cbf) Cbf += (long)z * zStride;
    }

    f32x4 acc[4][4];
#pragma unroll
    for (int i = 0; i < 4; i++)
#pragma unroll
        for (int j = 0; j < 4; j++) acc[i][j] = (f32x4){0.f, 0.f, 0.f, 0.f};

    // staging: 512 chunks of 8 bf16 per tile; 256 threads x 2 chunks
    const int c0 = tid, c1 = tid + 256;
    const int ar0 = c0 >> 2, ak0 = (c0 & 3) * 8;
    const int ar1 = c1 >> 2, ak1 = (c1 & 3) * 8;

    const bf16_t* Bptr = Bt + (long)n0 * K;

    for (int k0 = kBeg; k0 < kEnd; k0 += BK) {
        uint4 av0, av1;
        if constexpr (AF32) {
            const float* p0 = Af + (long)(m0 + ar0) * K + k0 + ak0;
            const float* p1 = Af + (long)(m0 + ar1) * K + k0 + ak1;
            float4 a00 = *(const float4*)p0, a01 = *(const float4*)(p0 + 4);
            float4 a10 = *(const float4*)p1, a11 = *(const float4*)(p1 + 4);
            av0 = pack_bf16x8(a00, a01);
            av1 = pack_bf16x8(a10, a11);
        } else {
            av0 = *(const uint4*)(A + (long)(m0 + ar0) * K + k0 + ak0);
            av1 = *(const uint4*)(A + (long)(m0 + ar1) * K + k0 + ak1);
        }
        uint4 bv0 = *(const uint4*)(Bptr + (long)ar0 * K + k0 + ak0);
        uint4 bv1 = *(const uint4*)(Bptr + (long)ar1 * K + k0 + ak1);
        __syncthreads();  // previous iteration's LDS reads complete
        *(uint4*)&As[ar0 * LDK + ak0] = av0;
        *(uint4*)&As[ar1 * LDK + ak1] = av1;
        *(uint4*)&Bs[ar0 * LDK + ak0] = bv0;
        *(uint4*)&Bs[ar1 * LDK + ak1] = bv1;
        __syncthreads();

        bf16x8 af[4], bfr[4];
#pragma unroll
        for (int i = 0; i < 4; i++) {
            af[i]  = *(bf16x8*)&As[(wm + i * 16 + lr) * LDK + lq * 8];
            bfr[i] = *(bf16x8*)&Bs[(wn + i * 16 + lr) * LDK + lq * 8];
        }
#pragma unroll
        for (int i = 0; i < 4; i++)
#pragma unroll
            for (int j = 0; j < 4; j++)
                acc[i][j] = __builtin_amdgcn_mfma_f32_16x16x32_bf16(
                    af[i], bfr[j], acc[i][j], 0, 0, 0);
    }

    // epilogue: D row = m0+wm+i*16+lq*4+r, col = n0+wn+j*16+lr
#pragma unroll
    for (int i = 0; i < 4; i++) {
#pragma unroll
        for (int j = 0; j < 4; j++) {
            const int col = n0 + wn + j * 16 + lr;
            const float bval = biasP ? biasP[col] : 0.f;
#pragma unroll
            for (int rr = 0; rr < 4; rr++) {
                const int row = m0 + wm + i * 16 + lq * 4 + rr;
                float v = acc[i][j][rr] + bval;
                if (relu) v = fmaxf(v, 0.f);
                const long idx = (long)row * N + col;
                if (Cf)  Cf[idx] = v;
                if (Cbf) Cbf[idx] = (bf16_t)v;
            }
        }
    }
}

// ---------------------------------------------------------------------------
// transpose + cast: in fp32 [R][C] row-major  ->  out bf16 [C][R] row-major
// R, C multiples of 32. block (32,8), 32x32 tiles, z = batch.
// ---------------------------------------------------------------------------
__global__ void transpose_cast(const float* __restrict__ in, bf16_t* __restrict__ out,
                               int R, int C, long inStrideZ, long outStrideZ)
{
    __shared__ float t[32][33];
    const float* inz = in + inStrideZ * blockIdx.z;
    bf16_t* outz = out + outStrideZ * blockIdx.z;
    const int c0 = blockIdx.x * 32;
    const int r0 = blockIdx.y * 32;
    const int tx = threadIdx.x, ty = threadIdx.y;
#pragma unroll
    for (int dy = 0; dy < 32; dy += 8)
        t[ty + dy][tx] = inz[(long)(r0 + ty + dy) * C + c0 + tx];
    __syncthreads();
#pragma unroll
    for (int dy = 0; dy < 32; dy += 8)
        outz[(long)(c0 + ty + dy) * R + r0 + tx] = (bf16_t)t[tx][ty + dy];
}

// ---------------------------------------------------------------------------
// WvN[i][d][h*64+e] = Wv[i][h][d][e]  (fp32 -> bf16), i.e. Wv_flat per layer
// ---------------------------------------------------------------------------
__global__ void build_wvn(const float* __restrict__ Wv, bf16_t* __restrict__ WvN)
{
    const long o = (long)blockIdx.x * 256 + threadIdx.x;  // 4*768*768 total
    const int e = (int)(o & 63);
    const int h = (int)((o >> 6) % 12);
    const long t = o / 768;
    const int d = (int)(t % 768);
    const int i = (int)(t / 768);
    WvN[o] = (bf16_t)Wv[(((long)(i * 12 + h) * 768 + d) << 6) + e];
}

// ---------------------------------------------------------------------------
// bvo[i][j] = bo[i][j] + sum_n bv[i][n] * Wo[i][n][j]   (all fp32, exact)
// ---------------------------------------------------------------------------
__global__ __launch_bounds__(256)
void build_bvo(const float* __restrict__ Wo, const float* __restrict__ bv,
               const float* __restrict__ bo, float* __restrict__ bvo)
{
    const int i = blockIdx.y;
    const int j = blockIdx.x * 256 + threadIdx.x;
    const float* w = Wo + (long)i * 589824 + j;
    const float* b = bv + i * 768;
    float s = bo[i * 768 + j];
    for (int n = 0; n < 768; n++) s += b[n] * w[(long)n * 768];
    bvo[i * 768 + j] = s;
}

// ---------------------------------------------------------------------------
// out = sum of nP bf16 partials, writes fp32 + bf16. 8 elems/thread.
// ---------------------------------------------------------------------------
__global__ __launch_bounds__(256)
void reduce_cast(const bf16_t* __restrict__ P, long pStride, int nP,
                 float* __restrict__ outF, bf16_t* __restrict__ outBf, long n)
{
    const long i = ((long)blockIdx.x * 256 + threadIdx.x) * 8;
    if (i + 8 > n) return;
    float s[8] = {0.f, 0.f, 0.f, 0.f, 0.f, 0.f, 0.f, 0.f};
    for (int p = 0; p < nP; p++) {
        bf16x8 v = *(const bf16x8*)(P + (long)p * pStride + i);
#pragma unroll
        for (int e = 0; e < 8; e++) s[e] += (float)v[e];
    }
    *(float4*)(outF + i)     = (float4){s[0], s[1], s[2], s[3]};
    *(float4*)(outF + i + 4) = (float4){s[4], s[5], s[6], s[7]};
    union { bf16_t h[8]; uint4 u; } cv;
#pragma unroll
    for (int e = 0; e < 8; e++) cv.h[e] = (bf16_t)s[e];
    *(uint4*)(outBf + i) = cv.u;
}

// ---------------------------------------------------------------------------
// X = LayerNorm(X + sum of nP bf16 partials)  (population var, no eps,
// no affine), writes fp32 + bf16. one block per row, D=768, 192 thr x 4 elems
// ---------------------------------------------------------------------------
__global__ __launch_bounds__(192)
void ln_residual(float* __restrict__ X, const bf16_t* __restrict__ P,
                 long pStride, int nP, bf16_t* __restrict__ Xbf)
{
    __shared__ float red[8];
    const long base = (long)blockIdx.x * 768;
    const int tid = threadIdx.x;
    const int i0 = tid * 4;
    float4 xv = *(const float4*)(X + base + i0);
    float s[4] = {xv.x, xv.y, xv.z, xv.w};
    for (int p = 0; p < nP; p++) {
        bf16x4 pv = *(const bf16x4*)(P + (long)p * pStride + base + i0);
        s[0] += (float)pv[0]; s[1] += (float)pv[1];
        s[2] += (float)pv[2]; s[3] += (float)pv[3];
    }
    float sum = s[0] + s[1] + s[2] + s[3];
    for (int o = 32; o > 0; o >>= 1) sum += __shfl_down(sum, o, 64);
    if ((tid & 63) == 0) red[tid >> 6] = sum;
    __syncthreads();
    const float mu = (red[0] + red[1] + red[2]) * (1.0f / 768.0f);
    float d0 = s[0] - mu, d1 = s[1] - mu, d2 = s[2] - mu, d3 = s[3] - mu;
    float sq = d0 * d0 + d1 * d1 + d2 * d2 + d3 * d3;
    for (int o = 32; o > 0; o >>= 1) sq += __shfl_down(sq, o, 64);
    if ((tid & 63) == 0) red[4 + (tid >> 6)] = sq;
    __syncthreads();
    const float var = (red[4] + red[5] + red[6]) * (1.0f / 768.0f);
    const float rstd = 1.0f / sqrtf(var);
    union { bf16_t h[4]; uint2 u; } cv;
#pragma unroll
    for (int j = 0; j < 4; j++) {
        const float v = (s[j] - mu) * rstd;
        X[base + i0 + j] = v;
        cv.h[j] = (bf16_t)v;
    }
    *(uint2*)(Xbf + base + i0) = cv.u;
}

// ---------------------------------------------------------------------------
// row softmax: reads bf16 logits [4096][8192], writes fp32 probabilities.
// one block per row, 256 threads, thread t owns elems g*2048 + t*8 .. +8
// ---------------------------------------------------------------------------
__global__ __launch_bounds__(256)
void softmax_bf16(const bf16_t* __restrict__ L, float* __restrict__ out)
{
    __shared__ float red[8];
    const long base = (long)blockIdx.x * 8192;
    const int tid = threadIdx.x;
    float v[32];
    float mx = -1e30f;
#pragma unroll
    for (int gq = 0; gq < 4; gq++) {
        bf16x8 h = *(const bf16x8*)(L + base + gq * 2048 + tid * 8);
#pragma unroll
        for (int e = 0; e < 8; e++) {
            v[gq * 8 + e] = (float)h[e];
            mx = fmaxf(mx, v[gq * 8 + e]);
        }
    }
    for (int o = 32; o > 0; o >>= 1) mx = fmaxf(mx, __shfl_down(mx, o, 64));
    if ((tid & 63) == 0) red[tid >> 6] = mx;
    __syncthreads();
    mx = fmaxf(fmaxf(red[0], red[1]), fmaxf(red[2], red[3]));
    float sum = 0.f;
#pragma unroll
    for (int j = 0; j < 32; j++) {
        v[j] = __expf(v[j] - mx);
        sum += v[j];
    }
    for (int o = 32; o > 0; o >>= 1) sum += __shfl_down(sum, o, 64);
    if ((tid & 63) == 0) red[4 + (tid >> 6)] = sum;
    __syncthreads();
    const float inv = 1.0f / (red[4] + red[5] + red[6] + red[7]);
#pragma unroll
    for (int gq = 0; gq < 4; gq++) {
        const long o0 = base + gq * 2048 + tid * 8;
        *(float4*)(out + o0) = (float4){v[gq*8+0]*inv, v[gq*8+1]*inv,
                                        v[gq*8+2]*inv, v[gq*8+3]*inv};
        *(float4*)(out + o0 + 4) = (float4){v[gq*8+4]*inv, v[gq*8+5]*inv,
                                            v[gq*8+6]*inv, v[gq*8+7]*inv};
    }
}

// ---------------------------------------------------------------------------
extern "C" void kernel_launch(void* const* d_in, const int* in_sizes, int n_in,
                              void* d_out, int out_size, void* d_ws, size_t ws_size,
                              hipStream_t stream)
{
    (void)in_sizes; (void)n_in; (void)out_size; (void)ws_size;
    const float* X0   = (const float*)d_in[0];
    const float* embw = (const float*)d_in[1];
    const float* embb = (const float*)d_in[2];
    // d_in[3..6] = Wq,bq,Wk,bk : unused (softmax rows sum to 1 => head_out == V)
    const float* Wv   = (const float*)d_in[7];
    const float* bv   = (const float*)d_in[8];
    const float* Wo   = (const float*)d_in[9];
    const float* bo   = (const float*)d_in[10];
    const float* W1   = (const float*)d_in[11];
    const float* b1   = (const float*)d_in[12];
    const float* W2   = (const float*)d_in[13];
    const float* b2   = (const float*)d_in[14];
    const float* Wout = (const float*)d_in[15];
    const float* bout = (const float*)d_in[16];
    float* out = (float*)d_out;

    // workspace layout (~149.4 MB), heavily time-shared:
    //   [0, 50.3 MB)    P: 8 x bf16[4096][768] split-K partials
    //                   phase-0 alias: WvN (4.7 MB) + WoT (4.7 MB)
    //   [50.3, 75.5)    Hid bf16[4096][3072]
    //   [0, 67.1)       final-phase alias: Lbf bf16[4096][8192] logits
    //   [75.5, 88.1)    embT (embed phase) / WoutT (final phase) -- disjoint
    char* base = (char*)d_ws;
    bf16_t* P     = (bf16_t*)base;                      // 50,331,648 B
    bf16_t* WvN   = (bf16_t*)base;                      // transient alias
    bf16_t* WoT   = (bf16_t*)(base + 4718592);          // transient alias
    bf16_t* Lbf   = (bf16_t*)base;                      // final-phase alias
    bf16_t* Hid   = (bf16_t*)(base + 50331648);         // 25,165,824 B
    bf16_t* embT  = (bf16_t*)(base + 75497472);         // 12,582,912 B
    bf16_t* WoutT = (bf16_t*)(base + 75497472);         // final-phase alias
    bf16_t* WvoT  = (bf16_t*)(base + 88080384);         //  4,718,592 B
    float*  bvo   = (float*)(base + 92798976);          //     12,288 B
    bf16_t* W1T   = (bf16_t*)(base + 92811264);         // 18,874,368 B
    bf16_t* W2T   = (bf16_t*)(base + 111685632);        // 18,874,368 B
    float*  Xf    = (float*)(base + 130560000);         // 12,582,912 B
    bf16_t* Xbf   = (bf16_t*)(base + 143142912);        //  6,291,456 B

    const dim3 tb(32, 8);
    const long MN = 3145728;  // 4096*768, partial stride (elements)

    // ---- phase 0: weight prep ------------------------------------------
    transpose_cast<<<dim3(24, 256, 1), tb, 0, stream>>>(embw, embT, 8192, 768, 0, 0);
    transpose_cast<<<dim3(24, 24, 4), tb, 0, stream>>>(Wo, WoT, 768, 768, 589824, 589824);
    build_wvn<<<9216, 256, 0, stream>>>(Wv, WvN);
    build_bvo<<<dim3(3, 4), 256, 0, stream>>>(Wo, bv, bo, bvo);
    // WvoT[i][j][d] = sum_n Wo[i][n][j] * Wv_flat[i][d][n]  (batched, bf16 out)
    gemm_bf16<false><<<dim3(6, 6, 4), 256, 0, stream>>>(
        WoT, nullptr, WvN, nullptr, nullptr, WvoT, 768, 768, 768, 0, 0, 589824L);
    transpose_cast<<<dim3(96, 24, 4), tb, 0, stream>>>(W1, W1T, 768, 3072, 2359296, 2359296);
    transpose_cast<<<dim3(24, 96, 4), tb, 0, stream>>>(W2, W2T, 3072, 768, 2359296, 2359296);

    // ---- phase 1: embedding, split-K=8 (bf16 partials), fp32 A direct --
    gemm_bf16<true><<<dim3(6, 32, 8), 256, 0, stream>>>(
        nullptr, X0, embT, embb, nullptr, P, 4096, 768, 8192, 0, 1024, 0);
    reduce_cast<<<1536, 256, 0, stream>>>(P, MN, 8, Xf, Xbf, MN);

    // ---- layers ---------------------------------------------------------
    for (int i = 0; i < 4; i++) {
        // O = X @ Wvo + bvo   (V and O GEMMs fused), split-K=4
        gemm_bf16<false><<<dim3(6, 32, 4), 256, 0, stream>>>(
            Xbf, nullptr, WvoT + (size_t)i * 589824, bvo + i * 768, nullptr, P,
            4096, 768, 768, 0, 192, 0);
        ln_residual<<<4096, 192, 0, stream>>>(Xf, P, MN, 4, Xbf);
        // Hid = relu(X @ W1 + b1)  (grid 768, no split needed)
        gemm_bf16<false><<<dim3(24, 32), 256, 0, stream>>>(
            Xbf, nullptr, W1T + (size_t)i * 2359296, b1 + i * 3072, nullptr, Hid,
            4096, 3072, 768, 1, 0, 0);
        // F = Hid @ W2 + b2, split-K=4 (bf16 partials)
        gemm_bf16<false><<<dim3(6, 32, 4), 256, 0, stream>>>(
            Hid, nullptr, W2T + (size_t)i * 2359296, b2 + i * 768, nullptr, P,
            4096, 768, 3072, 0, 768, 0);
        ln_residual<<<4096, 192, 0, stream>>>(Xf, P, MN, 4, Xbf);
    }

    // ---- phase 2: output head ------------------------------------------
    transpose_cast<<<dim3(256, 24, 1), tb, 0, stream>>>(Wout, WoutT, 768, 8192, 0, 0);
    gemm_bf16<false><<<dim3(64, 32), 256, 0, stream>>>(
        Xbf, nullptr, WoutT, bout, nullptr, Lbf, 4096, 8192, 768, 0, 0, 0);
    softmax_bf16<<<4096, 256, 0, stream>>>(Lbf, out);
}

// Round 4
// 1007.982 us; speedup vs baseline: 1.2812x; 1.0782x over previous
//
#include <hip/hip_runtime.h>

typedef __bf16 bf16_t;
typedef __bf16 bf16x4 __attribute__((ext_vector_type(4)));
typedef __bf16 bf16x8 __attribute__((ext_vector_type(8)));
typedef float f32x4 __attribute__((ext_vector_type(4)));

#define BM 128
#define BN 128
#define BK 32

// async global->LDS: 16 B per lane; LDS dest = wave-uniform base + lane*16 (HW)
__device__ __forceinline__ void gload16(const bf16_t* g, bf16_t* l)
{
    __builtin_amdgcn_global_load_lds(
        (const __attribute__((address_space(1))) void*)g,
        (__attribute__((address_space(3))) void*)l, 16, 0, 0);
}

// ---------------------------------------------------------------------------
// GEMM: C[M][N] = A[M][K] @ Bt[N][K]^T + bias[N], optional relu, fp32 and/or
// bf16 out. 128x128 tile, BK=32, 4 waves, 4x4 MFMA 16x16x32 per wave.
// Pipeline = catalog minimum 2-phase (T3 recipe), double-buffered LDS:
//   STAGE(buf[cur^1], tile t+1) ; ds_read buf[cur] ; MFMA ; __syncthreads()
// One vmcnt(0)+barrier per K-tile (inside __syncthreads) -- the prefetch gets
// the whole iteration's compute to land. No raw barriers, no asm waits.
// LDS layout: linear [128][32] bf16 per buffer (global_load_lds needs linear
// dest). Bank-conflict fix = both-sides XOR swizzle (rule #21): global source
// k-slot pre-swizzled (kslot ^= (row>>1)&3, an involution) and ds_read applies
// the same XOR -> logical data identical, 8-way read conflict -> ~2-way (free).
//   kChunk > 0: split-K; z = chunk; partial z -> (Cbf?Cbf:Cf)+z*M*N;
//               bias added only by chunk 0.
//   kChunk == 0 && zStride != 0: batched; A/Bt/Cf/Cbf offset z*zStride.
// All launches must satisfy (gridDim.y*gridDim.z) % 8 == 0 (XCD swizzle).
// ---------------------------------------------------------------------------
__global__ __launch_bounds__(256, 3)
void gemm_bf16(const bf16_t* __restrict__ A, const bf16_t* __restrict__ Bt,
               const float* __restrict__ bias,
               float* __restrict__ Cf, bf16_t* __restrict__ Cbf,
               int M, int N, int K, int relu, int kChunk, long zStride)
{
    __shared__ __align__(16) bf16_t As[2][BM * BK];
    __shared__ __align__(16) bf16_t Bs[2][BN * BK];

    // bijective XCD swizzle: co-locate blocks sharing the same A row-panel
    const int gx = gridDim.x, gy = gridDim.y;
    const long Lb = blockIdx.x + (long)gx * (blockIdx.y + (long)gy * blockIdx.z);
    const int  rb = (int)(Lb & 7);
    const long tbk = Lb >> 3;
    const int  bx = (int)(tbk % gx);
    const long gb = rb + 8 * (tbk / gx);
    const int  by = (int)(gb % gy);
    const int  bz = (int)(gb / gy);

    const int tid  = threadIdx.x;
    const int m0   = by * BM;
    const int n0   = bx * BN;
    const int wave = tid >> 6;
    const int lane = tid & 63;
    const int wm   = (wave & 1) * 64;   // wave row offset in block tile
    const int wn   = (wave >> 1) * 64;  // wave col offset
    const int lr   = lane & 15;         // A row / B col within 16-tile
    const int lq   = lane >> 4;         // quad 0..3 -> k-slot (8 elems each)

    int kBeg = 0, kEnd = K;
    const float* biasP = bias;
    if (kChunk > 0) {
        kBeg = bz * kChunk;
        kEnd = min(K, kBeg + kChunk);
        if (Cbf) Cbf += (long)bz * M * N;   // deterministic bf16 partial
        else     Cf  += (long)bz * M * N;
        if (bz != 0) biasP = nullptr;       // bias added exactly once
    } else if (zStride != 0) {
        A  += (long)bz * zStride;
        Bt += (long)bz * zStride;
        if (Cf)  Cf  += (long)bz * zStride;
        if (Cbf) Cbf += (long)bz * zStride;
    }

    f32x4 acc[4][4];
#pragma unroll
    for (int i = 0; i < 4; i++)
#pragma unroll
        for (int j = 0; j < 4; j++) acc[i][j] = (f32x4){0.f, 0.f, 0.f, 0.f};

    // staging chunks: c = wave*128 + {0,64} + lane; row = c>>2, kslot = c&3.
    // LDS elem offset = c*8 (linear, matches HW lane*16B). Source k-slot is
    // pre-swizzled so swizzled data lands in the linear dest (rule #21).
    const int c0  = wave * 128 + lane;
    const int c1  = c0 + 64;
    const int sw0 = ((c0 & 3) ^ ((c0 >> 3) & 3)) * 8;
    const int sw1 = ((c1 & 3) ^ ((c1 >> 3) & 3)) * 8;
    const bf16_t* gA0 = A  + (long)(m0 + (c0 >> 2)) * K + kBeg + sw0;
    const bf16_t* gA1 = A  + (long)(m0 + (c1 >> 2)) * K + kBeg + sw1;
    const bf16_t* gB0 = Bt + (long)(n0 + (c0 >> 2)) * K + kBeg + sw0;
    const bf16_t* gB1 = Bt + (long)(n0 + (c1 >> 2)) * K + kBeg + sw1;
    const int lb0 = wave * 1024;        // wave-uniform LDS elem base, chunk 0
    const int lb1 = wave * 1024 + 512;  // chunk 1
    const int lqx8 = (lq ^ ((lr >> 1) & 3)) * 8;  // swizzled read k-offset

    const int nt = (kEnd - kBeg) / BK;

    // prologue: stage tile 0 into buf 0
    gload16(gA0, &As[0][lb0]); gload16(gA1, &As[0][lb1]);
    gload16(gB0, &Bs[0][lb0]); gload16(gB1, &Bs[0][lb1]);
    __syncthreads();                    // vmcnt(0) drain + barrier

    long ko = BK;
    int cur = 0;
    for (int t = 0; t < nt; ++t) {
        if (t + 1 < nt) {               // prefetch tile t+1 into other buffer
            const int nx = cur ^ 1;
            gload16(gA0 + ko, &As[nx][lb0]); gload16(gA1 + ko, &As[nx][lb1]);
            gload16(gB0 + ko, &Bs[nx][lb0]); gload16(gB1 + ko, &Bs[nx][lb1]);
            ko += BK;
        }
        bf16x8 af[4], bfr[4];
#pragma unroll
        for (int i = 0; i < 4; i++) {
            af[i]  = *(const bf16x8*)&As[cur][(wm + i * 16 + lr) * BK + lqx8];
            bfr[i] = *(const bf16x8*)&Bs[cur][(wn + i * 16 + lr) * BK + lqx8];
        }
#pragma unroll
        for (int i = 0; i < 4; i++)
#pragma unroll
            for (int j = 0; j < 4; j++)
                acc[i][j] = __builtin_amdgcn_mfma_f32_16x16x32_bf16(
                    af[i], bfr[j], acc[i][j], 0, 0, 0);
        __syncthreads();                // prefetch landed; buf[cur] reusable
        cur ^= 1;
    }

    // epilogue: D row = m0+wm+i*16+lq*4+r, col = n0+wn+j*16+lr
#pragma unroll
    for (int i = 0; i < 4; i++) {
#pragma unroll
        for (int j = 0; j < 4; j++) {
            const int col = n0 + wn + j * 16 + lr;
            const float bval = biasP ? biasP[col] : 0.f;
#pragma unroll
            for (int rr = 0; rr < 4; rr++) {
                const int row = m0 + wm + i * 16 + lq * 4 + rr;
                float v = acc[i][j][rr] + bval;
                if (relu) v = fmaxf(v, 0.f);
                const long idx = (long)row * N + col;
                if (Cf)  Cf[idx] = v;
                if (Cbf) Cbf[idx] = (bf16_t)v;
            }
        }
    }
}

// ---------------------------------------------------------------------------
// fp32 -> bf16 elementwise cast (8 elems/thread), n % 8 == 0
// ---------------------------------------------------------------------------
__global__ __launch_bounds__(256)
void cast_bf16(const float* __restrict__ in, bf16_t* __restrict__ out, long n)
{
    long i = ((long)blockIdx.x * blockDim.x + threadIdx.x) * 8;
    if (i + 8 > n) return;
    float4 f0 = *(const float4*)(in + i);
    float4 f1 = *(const float4*)(in + i + 4);
    union { bf16_t h[8]; uint4 u; } cv;
    cv.h[0] = (bf16_t)f0.x; cv.h[1] = (bf16_t)f0.y;
    cv.h[2] = (bf16_t)f0.z; cv.h[3] = (bf16_t)f0.w;
    cv.h[4] = (bf16_t)f1.x; cv.h[5] = (bf16_t)f1.y;
    cv.h[6] = (bf16_t)f1.z; cv.h[7] = (bf16_t)f1.w;
    *(uint4*)(out + i) = cv.u;
}

// ---------------------------------------------------------------------------
// transpose + cast: in fp32 [R][C] row-major  ->  out bf16 [C][R] row-major
// ---------------------------------------------------------------------------
__global__ void transpose_cast(const float* __restrict__ in, bf16_t* __restrict__ out,
                               int R, int C, long inStrideZ, long outStrideZ)
{
    __shared__ float t[32][33];
    const float* inz = in + inStrideZ * blockIdx.z;
    bf16_t* outz = out + outStrideZ * blockIdx.z;
    const int c0 = blockIdx.x * 32;
    const int r0 = blockIdx.y * 32;
    const int tx = threadIdx.x, ty = threadIdx.y;
#pragma unroll
    for (int dy = 0; dy < 32; dy += 8)
        t[ty + dy][tx] = inz[(long)(r0 + ty + dy) * C + c0 + tx];
    __syncthreads();
#pragma unroll
    for (int dy = 0; dy < 32; dy += 8)
        outz[(long)(c0 + ty + dy) * R + r0 + tx] = (bf16_t)t[tx][ty + dy];
}

// ---------------------------------------------------------------------------
// WvN[i][d][h*64+e] = Wv[i][h][d][e]  (fp32 -> bf16), i.e. Wv_flat per layer
// ---------------------------------------------------------------------------
__global__ void build_wvn(const float* __restrict__ Wv, bf16_t* __restrict__ WvN)
{
    const long o = (long)blockIdx.x * 256 + threadIdx.x;  // 4*768*768 total
    const int e = (int)(o & 63);
    const int h = (int)((o >> 6) % 12);
    const long t = o / 768;
    const int d = (int)(t % 768);
    const int i = (int)(t / 768);
    WvN[o] = (bf16_t)Wv[(((long)(i * 12 + h) * 768 + d) << 6) + e];
}

// ---------------------------------------------------------------------------
// bvo[i][j] = bo[i][j] + sum_n bv[i][n] * Wo[i][n][j]   (all fp32, exact)
// ---------------------------------------------------------------------------
__global__ __launch_bounds__(256)
void build_bvo(const float* __restrict__ Wo, const float* __restrict__ bv,
               const float* __restrict__ bo, float* __restrict__ bvo)
{
    const int i = blockIdx.y;
    const int j = blockIdx.x * 256 + threadIdx.x;
    const float* w = Wo + (long)i * 589824 + j;
    const float* b = bv + i * 768;
    float s = bo[i * 768 + j];
    for (int n = 0; n < 768; n++) s += b[n] * w[(long)n * 768];
    bvo[i * 768 + j] = s;
}

// ---------------------------------------------------------------------------
// out = sum of nP bf16 partials, writes fp32 + bf16. 8 elems/thread.
// ---------------------------------------------------------------------------
__global__ __launch_bounds__(256)
void reduce_cast(const bf16_t* __restrict__ P, long pStride, int nP,
                 float* __restrict__ outF, bf16_t* __restrict__ outBf, long n)
{
    const long i = ((long)blockIdx.x * 256 + threadIdx.x) * 8;
    if (i + 8 > n) return;
    float s[8] = {0.f, 0.f, 0.f, 0.f, 0.f, 0.f, 0.f, 0.f};
    for (int p = 0; p < nP; p++) {
        bf16x8 v = *(const bf16x8*)(P + (long)p * pStride + i);
#pragma unroll
        for (int e = 0; e < 8; e++) s[e] += (float)v[e];
    }
    *(float4*)(outF + i)     = (float4){s[0], s[1], s[2], s[3]};
    *(float4*)(outF + i + 4) = (float4){s[4], s[5], s[6], s[7]};
    union { bf16_t h[8]; uint4 u; } cv;
#pragma unroll
    for (int e = 0; e < 8; e++) cv.h[e] = (bf16_t)s[e];
    *(uint4*)(outBf + i) = cv.u;
}

// ---------------------------------------------------------------------------
// X = LayerNorm(X + sum of nP bf16 partials), writes fp32 + bf16.
// one block per row, D = 768, 192 threads x 4 elems
// ---------------------------------------------------------------------------
__global__ __launch_bounds__(192)
void ln_residual(float* __restrict__ X, const bf16_t* __restrict__ P,
                 long pStride, int nP, bf16_t* __restrict__ Xbf)
{
    __shared__ float red[8];
    const long base = (long)blockIdx.x * 768;
    const int tid = threadIdx.x;
    const int i0 = tid * 4;
    float4 xv = *(const float4*)(X + base + i0);
    float s[4] = {xv.x, xv.y, xv.z, xv.w};
    for (int p = 0; p < nP; p++) {
        bf16x4 pv = *(const bf16x4*)(P + (long)p * pStride + base + i0);
        s[0] += (float)pv[0]; s[1] += (float)pv[1];
        s[2] += (float)pv[2]; s[3] += (float)pv[3];
    }
    float sum = s[0] + s[1] + s[2] + s[3];
    for (int o = 32; o > 0; o >>= 1) sum += __shfl_down(sum, o, 64);
    if ((tid & 63) == 0) red[tid >> 6] = sum;
    __syncthreads();
    const float mu = (red[0] + red[1] + red[2]) * (1.0f / 768.0f);
    float d0 = s[0] - mu, d1 = s[1] - mu, d2 = s[2] - mu, d3 = s[3] - mu;
    float sq = d0 * d0 + d1 * d1 + d2 * d2 + d3 * d3;
    for (int o = 32; o > 0; o >>= 1) sq += __shfl_down(sq, o, 64);
    if ((tid & 63) == 0) red[4 + (tid >> 6)] = sq;
    __syncthreads();
    const float var = (red[4] + red[5] + red[6]) * (1.0f / 768.0f);
    const float rstd = 1.0f / sqrtf(var);
    union { bf16_t h[4]; uint2 u; } cv;
#pragma unroll
    for (int j = 0; j < 4; j++) {
        const float v = (s[j] - mu) * rstd;
        X[base + i0 + j] = v;
        cv.h[j] = (bf16_t)v;
    }
    *(uint2*)(Xbf + base + i0) = cv.u;
}

// ---------------------------------------------------------------------------
// row softmax: reads bf16 logits [4096][8192], writes fp32 probabilities.
// ---------------------------------------------------------------------------
__global__ __launch_bounds__(256)
void softmax_bf16(const bf16_t* __restrict__ L, float* __restrict__ out)
{
    __shared__ float red[8];
    const long base = (long)blockIdx.x * 8192;
    const int tid = threadIdx.x;
    float v[32];
    float mx = -1e30f;
#pragma unroll
    for (int gq = 0; gq < 4; gq++) {
        bf16x8 h = *(const bf16x8*)(L + base + gq * 2048 + tid * 8);
#pragma unroll
        for (int e = 0; e < 8; e++) {
            v[gq * 8 + e] = (float)h[e];
            mx = fmaxf(mx, v[gq * 8 + e]);
        }
    }
    for (int o = 32; o > 0; o >>= 1) mx = fmaxf(mx, __shfl_down(mx, o, 64));
    if ((tid & 63) == 0) red[tid >> 6] = mx;
    __syncthreads();
    mx = fmaxf(fmaxf(red[0], red[1]), fmaxf(red[2], red[3]));
    float sum = 0.f;
#pragma unroll
    for (int j = 0; j < 32; j++) {
        v[j] = __expf(v[j] - mx);
        sum += v[j];
    }
    for (int o = 32; o > 0; o >>= 1) sum += __shfl_down(sum, o, 64);
    if ((tid & 63) == 0) red[4 + (tid >> 6)] = sum;
    __syncthreads();
    const float inv = 1.0f / (red[4] + red[5] + red[6] + red[7]);
#pragma unroll
    for (int gq = 0; gq < 4; gq++) {
        const long o0 = base + gq * 2048 + tid * 8;
        *(float4*)(out + o0) = (float4){v[gq*8+0]*inv, v[gq*8+1]*inv,
                                        v[gq*8+2]*inv, v[gq*8+3]*inv};
        *(float4*)(out + o0 + 4) = (float4){v[gq*8+4]*inv, v[gq*8+5]*inv,
                                            v[gq*8+6]*inv, v[gq*8+7]*inv};
    }
}

// ---------------------------------------------------------------------------
extern "C" void kernel_launch(void* const* d_in, const int* in_sizes, int n_in,
                              void* d_out, int out_size, void* d_ws, size_t ws_size,
                              hipStream_t stream)
{
    (void)in_sizes; (void)n_in; (void)out_size; (void)ws_size;
    const float* X0   = (const float*)d_in[0];
    const float* embw = (const float*)d_in[1];
    const float* embb = (const float*)d_in[2];
    // d_in[3..6] = Wq,bq,Wk,bk : unused (softmax rows sum to 1 => head_out == V)
    const float* Wv   = (const float*)d_in[7];
    const float* bv   = (const float*)d_in[8];
    const float* Wo   = (const float*)d_in[9];
    const float* bo   = (const float*)d_in[10];
    const float* W1   = (const float*)d_in[11];
    const float* b1   = (const float*)d_in[12];
    const float* W2   = (const float*)d_in[13];
    const float* b2   = (const float*)d_in[14];
    const float* Wout = (const float*)d_in[15];
    const float* bout = (const float*)d_in[16];
    float* out = (float*)d_out;

    // workspace layout: 141,045,760 B total (< 149.4 MB proven in rounds 0-2).
    //  R0 [0, 67.1 MB): X0bf (cast -> embed GEMM); after embed, reused as
    //      Xf [0,12.6) + W1T [12.6,31.5) + W2T [31.5,50.3); in output phase
    //      Lbf logits [0,67.1) overwrite Xf/W1T/W2T (all dead by then).
    //  [67.1, 92.3): P = 4 x bf16[4096][768] split-K partials;
    //      prep transients WvN [67.1,71.8) + WoT [71.8,76.5) alias P (dead
    //      before P's first write).
    //  [92.3, 117.4): Hid bf16[4096][3072]
    //  [117.4, 130.0): embT -> WoutT (output phase alias)
    //  [130.0, 134.7): WvoT   [134.7, +12KB): bvo   [134.75, 141.0): Xbf
    char* base = (char*)d_ws;
    bf16_t* X0bf  = (bf16_t*)base;
    float*  Xf    = (float*)base;
    bf16_t* W1T   = (bf16_t*)(base + 12582912);
    bf16_t* W2T   = (bf16_t*)(base + 31457280);
    bf16_t* Lbf   = (bf16_t*)base;
    bf16_t* P     = (bf16_t*)(base + 67108864);
    bf16_t* WvN   = (bf16_t*)(base + 67108864);         // prep transient
    bf16_t* WoT   = (bf16_t*)(base + 71827456);         // prep transient
    bf16_t* Hid   = (bf16_t*)(base + 92274688);
    bf16_t* embT  = (bf16_t*)(base + 117440512);
    bf16_t* WoutT = (bf16_t*)(base + 117440512);        // output-phase alias
    bf16_t* WvoT  = (bf16_t*)(base + 130023424);
    float*  bvo   = (float*)(base + 134742016);
    bf16_t* Xbf   = (bf16_t*)(base + 134754304);

    const dim3 tb(32, 8);
    const long MN = 3145728;  // 4096*768, partial stride (elements)

    // ---- phase 0: input cast + weight prep -----------------------------
    cast_bf16<<<16384, 256, 0, stream>>>(X0, X0bf, (long)33554432);
    transpose_cast<<<dim3(24, 256, 1), tb, 0, stream>>>(embw, embT, 8192, 768, 0, 0);
    transpose_cast<<<dim3(24, 24, 4), tb, 0, stream>>>(Wo, WoT, 768, 768, 589824, 589824);
    build_wvn<<<9216, 256, 0, stream>>>(Wv, WvN);
    build_bvo<<<dim3(3, 4), 256, 0, stream>>>(Wo, bv, bo, bvo);
    // WvoT[i][j][d] = sum_n Wo[i][n][j] * Wv_flat[i][d][n]  (batched)
    gemm_bf16<<<dim3(6, 6, 4), 256, 0, stream>>>(
        WoT, WvN, nullptr, nullptr, WvoT, 768, 768, 768, 0, 0, 589824L);

    // ---- phase 1: embedding, split-K=4 (bf16 partials) -----------------
    gemm_bf16<<<dim3(6, 32, 4), 256, 0, stream>>>(
        X0bf, embT, embb, nullptr, P, 4096, 768, 8192, 0, 2048, 0);
    reduce_cast<<<1536, 256, 0, stream>>>(P, MN, 4, Xf, Xbf, MN);

    // X0bf dead: build W1T/W2T into R0 now
    transpose_cast<<<dim3(96, 24, 4), tb, 0, stream>>>(W1, W1T, 768, 3072, 2359296, 2359296);
    transpose_cast<<<dim3(24, 96, 4), tb, 0, stream>>>(W2, W2T, 3072, 768, 2359296, 2359296);

    // ---- layers ---------------------------------------------------------
    for (int i = 0; i < 4; i++) {
        // O = X @ Wvo + bvo   (V and O GEMMs fused), split-K=4
        gemm_bf16<<<dim3(6, 32, 4), 256, 0, stream>>>(
            Xbf, WvoT + (size_t)i * 589824, bvo + i * 768, nullptr, P,
            4096, 768, 768, 0, 192, 0);
        ln_residual<<<4096, 192, 0, stream>>>(Xf, P, MN, 4, Xbf);
        // Hid = relu(X @ W1 + b1)
        gemm_bf16<<<dim3(24, 32), 256, 0, stream>>>(
            Xbf, W1T + (size_t)i * 2359296, b1 + i * 3072, nullptr, Hid,
            4096, 3072, 768, 1, 0, 0);
        // F = Hid @ W2 + b2, split-K=4
        gemm_bf16<<<dim3(6, 32, 4), 256, 0, stream>>>(
            Hid, W2T + (size_t)i * 2359296, b2 + i * 768, nullptr, P,
            4096, 768, 3072, 0, 768, 0);
        ln_residual<<<4096, 192, 0, stream>>>(Xf, P, MN, 4, Xbf);
    }

    // ---- phase 2: output head ------------------------------------------
    transpose_cast<<<dim3(256, 24, 1), tb, 0, stream>>>(Wout, WoutT, 768, 8192, 0, 0);
    gemm_bf16<<<dim3(64, 32), 256, 0, stream>>>(
        Xbf, WoutT, bout, nullptr, Lbf, 4096, 8192, 768, 0, 0, 0);
    softmax_bf16<<<4096, 256, 0, stream>>>(Lbf, out);
}